// Round 7
// baseline (313.400 us; speedup 1.0000x reference)
//
#include <hip/hip_runtime.h>
#include <math.h>

// Problem constants (from reference): N=50000, E=800000, IN=256, H=4, F=64.
constexpr float SLOPE = 0.2f;

typedef __bf16 bf16x8 __attribute__((ext_vector_type(8)));
typedef __bf16 bf16x4 __attribute__((ext_vector_type(4)));
typedef float  f32x4  __attribute__((ext_vector_type(4)));

__device__ __forceinline__ int imin(int a, int b) { return a < b ? a : b; }

// Async global->LDS 16B copy. LDS dest must be lane-linear (wave-uniform base
// + lane*16) — our staging index order matches lane order exactly.
__device__ __forceinline__ void glds16(const void* g, void* l) {
    __builtin_amdgcn_global_load_lds(
        (const __attribute__((address_space(1))) unsigned int*)g,
        (__attribute__((address_space(3))) unsigned int*)l,
        16, 0, 0);
}

// ---------------------------------------------------------------------------
// Fused prep: [0,512) Bt transpose+cast | [512,512+nxb) x->bf16 cast |
// rest: target-degree histogram.
// ---------------------------------------------------------------------------
__global__ __launch_bounds__(256) void prep_k(
    const float* __restrict__ W, const float* __restrict__ skw,
    __bf16* __restrict__ Bt,
    const float* __restrict__ x, __bf16* __restrict__ xb, int nxv, int nxb,
    const int* __restrict__ etrg, int* __restrict__ cnt, int E)
{
    const int b = blockIdx.x;
    if (b < 512) {
        const int i = b * 256 + threadIdx.x;     // i = n*256 + k
        const int n = i >> 8, k = i & 255;
        const float v = (n < 256) ? W[k * 256 + n] : skw[k * 256 + (n - 256)];
        Bt[i] = (__bf16)v;
    } else if (b < 512 + nxb) {
        const int gid = (b - 512) * 256 + threadIdx.x;   // 8 f32 per thread
        if (gid < nxv) {
            const float4 f0 = *(const float4*)(x + (size_t)gid * 8);
            const float4 f1 = *(const float4*)(x + (size_t)gid * 8 + 4);
            bf16x8 v;
            v[0] = (__bf16)f0.x; v[1] = (__bf16)f0.y;
            v[2] = (__bf16)f0.z; v[3] = (__bf16)f0.w;
            v[4] = (__bf16)f1.x; v[5] = (__bf16)f1.y;
            v[6] = (__bf16)f1.z; v[7] = (__bf16)f1.w;
            *(bf16x8*)(xb + (size_t)gid * 8) = v;
        }
    } else {
        const int e = (b - 512 - nxb) * 256 + threadIdx.x;
        if (e < E) atomicAdd(&cnt[etrg[e]], 1);
    }
}

// ---------------------------------------------------------------------------
// MFMA GEMM, 256x128 tile: C[M,512] = xb[M,256] @ [W | skip_w].
// 1D grid, y = bid&3 INNERMOST so the 4 blocks sharing an A-tile dispatch
// back-to-back (L2/L3-temporal reuse of the 131KB xb tile).
// y=0,1 -> projb bf16 cols 0..255; y=2,3 -> out f32 (skip) cols 256..511.
// y=0,1 blocks ALSO compute the attention scores, fused INTO the C-write
// loop (single pass over acc: each acc[rb][cb][r] is read exactly once, so
// accumulator registers die progressively — the R6 two-pass epilogue kept
// all 128 acc f32 live across the whole C-write and spilled: VGPR 124,
// occupancy 16.5%, 95us).
// shfl_xor d in {1,2,4,8} only permutes ln bits: partners share q hence the
// same grow predicate, so the reduction is exec-mask-safe inside grow<M.
// BK=32, 4 waves; A/B frag: [m|n]=lane&15, k=quad*8+j; C/D: col=lane&15,
// row=quad*4+reg.
// ---------------------------------------------------------------------------
__global__ __launch_bounds__(256, 2) void gemm_mfma(
    const __bf16* __restrict__ xb, const __bf16* __restrict__ Bt,
    __bf16* __restrict__ projb, float* __restrict__ out,
    const float* __restrict__ a_src, const float* __restrict__ a_trg,
    float* __restrict__ s_src, float* __restrict__ s_trg, int M)
{
    __shared__ __bf16 As[256 * 32];   // 16 KB
    __shared__ __bf16 Bs[128 * 32];   //  8 KB

    const int t    = threadIdx.x;
    const int w    = t >> 6;
    const int lane = t & 63;
    const int q    = lane >> 4;
    const int ln   = lane & 15;

    const int bid  = blockIdx.x;
    const int bx   = bid >> 2;
    const int y    = bid & 3;
    const int row0 = bx * 256;
    const int bt0  = y * 128;              // Bt row base (Bt row = global col)

    f32x4 acc[4][8] = {};

    for (int k0 = 0; k0 < 256; k0 += 32) {
#pragma unroll
        for (int p = 0; p < 4; ++p) {          // A: 256 rows x 32 k
            const int idx = p * 256 + t;
            const int r   = idx >> 2;          // 0..255
            const int ko  = (idx & 3) * 8;     // 0,8,16,24
            const int ga  = imin(row0 + r, M - 1);
            glds16(xb + (size_t)ga * 256 + k0 + ko, &As[idx * 8]);
        }
#pragma unroll
        for (int p = 0; p < 2; ++p) {          // B: 128 rows x 32 k
            const int idx = p * 256 + t;
            const int r   = idx >> 2;          // 0..127
            const int ko  = (idx & 3) * 8;
            glds16(Bt + (size_t)(bt0 + r) * 256 + k0 + ko, &Bs[idx * 8]);
        }
        asm volatile("s_waitcnt vmcnt(0)" ::: "memory");
        __syncthreads();

        bf16x8 af[4], bfr[8];
#pragma unroll
        for (int rb = 0; rb < 4; ++rb)
            af[rb] = *(const bf16x8*)&As[(w * 64 + rb * 16 + ln) * 32 + q * 8];
#pragma unroll
        for (int cb = 0; cb < 8; ++cb)
            bfr[cb] = *(const bf16x8*)&Bs[(cb * 16 + ln) * 32 + q * 8];
#pragma unroll
        for (int rb = 0; rb < 4; ++rb)
#pragma unroll
            for (int cb = 0; cb < 8; ++cb)
                acc[rb][cb] = __builtin_amdgcn_mfma_f32_16x16x32_bf16(
                    af[rb], bfr[cb], acc[rb][cb], 0, 0, 0);
        __syncthreads();
    }

    const bool isProj  = (y < 2);
    const int  colbase = (y & 1) * 128;

    // Per-lane score weights (y<2 only): lane owns cols cb*16+ln.
    float as[8], at[8];
    if (isProj) {
#pragma unroll
        for (int cb = 0; cb < 8; ++cb) {
            const int lcol = cb * 16 + ln;          // 0..127 local col
            const int hh   = y * 2 + (lcol >> 6);   // head
            const int f    = lcol & 63;
            as[cb] = a_src[hh * 64 + f];
            at[cb] = a_trg[hh * 64 + f];
        }
    }

#pragma unroll
    for (int rb = 0; rb < 4; ++rb) {
#pragma unroll
        for (int r = 0; r < 4; ++r) {
            const int grow = row0 + w * 64 + rb * 16 + q * 4 + r;
            if (grow < M) {
                float s0 = 0.f, s1 = 0.f, t0 = 0.f, t1 = 0.f;
#pragma unroll
                for (int cb = 0; cb < 8; ++cb) {
                    const float v = acc[rb][cb][r];   // single read of acc
                    const int gcol = colbase + cb * 16 + ln;
                    if (isProj) {
                        projb[(size_t)grow * 256 + gcol] = (__bf16)v;
                        if (cb < 4) { s0 += v * as[cb]; t0 += v * at[cb]; }
                        else        { s1 += v * as[cb]; t1 += v * at[cb]; }
                    } else {
                        out[(size_t)grow * 256 + gcol] = v;
                    }
                }
                if (isProj) {
#pragma unroll
                    for (int d = 1; d < 16; d <<= 1) {   // reduce over ln
                        s0 += __shfl_xor(s0, d);
                        s1 += __shfl_xor(s1, d);
                        t0 += __shfl_xor(t0, d);
                        t1 += __shfl_xor(t1, d);
                    }
                    if (ln == 0) {
                        s_src[grow * 4 + y * 2]     = s0;
                        s_src[grow * 4 + y * 2 + 1] = s1;
                        s_trg[grow * 4 + y * 2]     = t0;
                        s_trg[grow * 4 + y * 2 + 1] = t1;
                    }
                }
            }
        }
    }
}

// ---------------------------------------------------------------------------
// Scan phase A: block-local exclusive scan of 1024-elem chunks.
// ---------------------------------------------------------------------------
__global__ __launch_bounds__(1024) void scanA(
    const int* __restrict__ cnt, int* __restrict__ off, int* __restrict__ bsum, int N)
{
    __shared__ int wsum[16];
    const int t = threadIdx.x;
    const int lane = t & 63;
    const int w = t >> 6;
    const int i = blockIdx.x * 1024 + t;
    const int v = (i < N) ? cnt[i] : 0;

    int s = v;
#pragma unroll
    for (int d = 1; d < 64; d <<= 1) {
        int o = __shfl_up(s, d);
        if (lane >= d) s += o;
    }
    if (lane == 63) wsum[w] = s;
    __syncthreads();
    if (w == 0 && lane < 16) {
        int ws = wsum[lane];
        int sc = ws;
#pragma unroll
        for (int d = 1; d < 16; d <<= 1) {
            int o = __shfl_up(sc, d);
            if (lane >= d) sc += o;
        }
        wsum[lane] = sc - ws;
    }
    __syncthreads();
    const int excl = wsum[w] + s - v;
    if (i < N) off[i] = excl;
    if (t == 1023) bsum[blockIdx.x] = excl + v;
}

// ---------------------------------------------------------------------------
// Scan phase BC fused: each block sums its <=49 preceding chunk totals.
// ---------------------------------------------------------------------------
__global__ __launch_bounds__(256) void scanBC(
    int* __restrict__ off, const int* __restrict__ bsum, int* __restrict__ cur,
    int N, int E)
{
    const int i = blockIdx.x * 256 + threadIdx.x;
    const int chunk = blockIdx.x >> 2;
    const int lane = threadIdx.x & 63;

    int v = (lane < chunk) ? bsum[lane] : 0;
#pragma unroll
    for (int d = 1; d < 64; d <<= 1) v += __shfl_xor(v, d);

    if (i < N) {
        const int o = off[i] + v;
        off[i] = o;
        cur[i] = o;
    }
    if (i == 0) off[N] = E;
}

// ---------------------------------------------------------------------------
// Scatter: target-sorted srcs only (4 B/edge — exp weights are computed
// in-aggregate via lane-split + shuffle, no exs array).
// ---------------------------------------------------------------------------
__global__ __launch_bounds__(256) void scatter_k(
    const int* __restrict__ esrc, const int* __restrict__ etrg,
    int* __restrict__ cur, int* __restrict__ srcs, int E)
{
    const int e = blockIdx.x * 256 + threadIdx.x;
    if (e < E) {
        const int pos = atomicAdd(&cur[etrg[e]], 1);
        srcs[pos] = esrc[e];
    }
}

// ---------------------------------------------------------------------------
// Fused softmax + aggregation + skip + bias + activation.
// ONE WAVE per target node (4 nodes/block). Lane l owns feature elems
// 4l..4l+3 (bf16x4 = 8 B gather/lane), head h = l>>4.
//
// Per 8-edge batch: batch base i is wave-uniform (off[] readfirstlane'd), so
// the 8 src ids are lifted to SGPRs via v_readlane (no ds_bpermute chain) and
// gathers issue as saddr-form loads. Lane (h*16+j') computes exp(edge j',
// head h) once; e[j] distributed via one bpermute per edge.
//
// 2-deep software pipeline (A/B ping-pong, statically indexed): batch k+1's
// srcs load + s_src gather + exp + 8 projb gathers are issued BEFORE batch
// k's e-shuffles + FMAs, so gather latency hides under consume. Global-max
// shift of the reference cancels in ex/denom. out already holds the skip
// projection (gemm y=2,3).
// ---------------------------------------------------------------------------
__global__ __launch_bounds__(256) void aggregate_wave(
    const int* __restrict__ off, const int* __restrict__ srcs,
    const float* __restrict__ s_src, const float* __restrict__ s_trg,
    const __bf16* __restrict__ projb, const float* __restrict__ bias,
    float* __restrict__ out, int N)
{
    const int w = threadIdx.x >> 6;
    const int l = threadIdx.x & 63;
    const int n = blockIdx.x * 4 + w;
    if (n >= N) return;

    const int h  = l >> 4;
    const int je = l & 7;
    const float st = s_trg[n * 4 + h];
    const int b0 = __builtin_amdgcn_readfirstlane(off[n]);
    const int b1 = __builtin_amdgcn_readfirstlane(off[n + 1]);

    f32x4 acc = {0.f, 0.f, 0.f, 0.f};
    float denom = 0.f;

    int i = b0;
    const int nb = (b1 - b0) >> 3;

    int    sgA[8], sgB[8];
    bf16x4 pA[8], pB[8];
    float  exA, exB;

    // Issue batch at position i: uniform src ids -> SGPR, gathers in flight,
    // this lane's exp for (edge je, head h). Advances i.
#define ISSUE(SG, P, EX)                                                      \
    {                                                                         \
        const int sm = srcs[i + je];                                          \
        _Pragma("unroll")                                                     \
        for (int j = 0; j < 8; ++j) SG[j] = __builtin_amdgcn_readlane(sm, j); \
        _Pragma("unroll")                                                     \
        for (int j = 0; j < 8; ++j)                                           \
            P[j] = *(const bf16x4*)(projb +                                   \
                     (size_t)((unsigned)SG[j] * 256u) + l * 4);               \
        float v = s_src[sm * 4 + h] + st;                                     \
        v = v > 0.f ? v : SLOPE * v;                                          \
        EX = __expf(v);                                                       \
        i += 8;                                                               \
    }

    // Consume a batch: distribute exp weights (1 bpermute/edge) and FMA.
#define CONSUME(P, EX)                                                        \
    {                                                                         \
        _Pragma("unroll")                                                     \
        for (int j = 0; j < 8; ++j) {                                         \
            const float e = __shfl(EX, (l & 48) | j);                         \
            denom += e;                                                       \
            acc[0] += e * (float)P[j][0];                                     \
            acc[1] += e * (float)P[j][1];                                     \
            acc[2] += e * (float)P[j][2];                                     \
            acc[3] += e * (float)P[j][3];                                     \
        }                                                                     \
    }

    if (nb > 0) {
        ISSUE(sgA, pA, exA);
        int rem = nb - 1;
        while (rem >= 2) {
            ISSUE(sgB, pB, exB);
            CONSUME(pA, exA);
            ISSUE(sgA, pA, exA);
            CONSUME(pB, exB);
            rem -= 2;
        }
        if (rem == 1) {
            ISSUE(sgB, pB, exB);
            CONSUME(pA, exA);
            CONSUME(pB, exB);
        } else {
            CONSUME(pA, exA);
        }
    }
#undef ISSUE
#undef CONSUME

    for (; i < b1; ++i) {
        const int s = srcs[i];
        float v = s_src[s * 4 + h] + st;
        v = v > 0.f ? v : SLOPE * v;
        const float ex = __expf(v);
        denom += ex;
        const bf16x4 p = *(const bf16x4*)(projb + (size_t)((unsigned)s * 256u) + l * 4);
        acc[0] += ex * (float)p[0];
        acc[1] += ex * (float)p[1];
        acc[2] += ex * (float)p[2];
        acc[3] += ex * (float)p[3];
    }

    const size_t o = (size_t)n * 256 + l * 4;
    const float4 sk = *(const float4*)(out + o);
    const float4 b4 = *(const float4*)(bias + l * 4);
    const float inv = 1.f / (denom + 1e-16f);
    float4 r;
    r.x = acc[0] * inv + sk.x + b4.x;
    r.y = acc[1] * inv + sk.y + b4.y;
    r.z = acc[2] * inv + sk.z + b4.z;
    r.w = acc[3] * inv + sk.w + b4.w;
    r.x = r.x > 0.f ? r.x : SLOPE * r.x;
    r.y = r.y > 0.f ? r.y : SLOPE * r.y;
    r.z = r.z > 0.f ? r.z : SLOPE * r.z;
    r.w = r.w > 0.f ? r.w : SLOPE * r.w;
    *(float4*)(out + o) = r;
}

extern "C" void kernel_launch(void* const* d_in, const int* in_sizes, int n_in,
                              void* d_out, int out_size, void* d_ws, size_t ws_size,
                              hipStream_t stream)
{
    const float* x     = (const float*)d_in[0];
    const float* W     = (const float*)d_in[1];
    const float* a_src = (const float*)d_in[2];
    const float* a_trg = (const float*)d_in[3];
    const float* skw   = (const float*)d_in[4];
    const float* bias  = (const float*)d_in[5];
    const int*   esrc  = (const int*)d_in[6];
    const int*   etrg  = (const int*)d_in[7];

    const int N = in_sizes[0] / 256;   // 50000
    const int E = in_sizes[6];         // 800000
    float* out = (float*)d_out;

    // workspace: projb bf16[N*256] | Bt bf16[512*256] | xb bf16[N*256] |
    //            s_src f32[4N] | s_trg f32[4N] | cnt[N] | off[N+1] | cur[N] |
    //            bsum[64] | srcs[E]
    __bf16* projb = (__bf16*)d_ws;
    __bf16* Bt    = projb + (size_t)N * 256;
    __bf16* xb    = Bt + 512 * 256;
    float*  s_src = (float*)(xb + (size_t)N * 256);
    float*  s_trg = s_src + (size_t)N * 4;
    int*    cnt   = (int*)(s_trg + (size_t)N * 4);
    int*    off   = cnt + N;
    int*    cur   = off + (N + 1);
    int*    bsum  = cur + N;
    int*    srcs  = bsum + 64;

    const int nxv = (N * 256) / 8;
    const int nxb = (nxv + 255) / 256;
    const int nhb = (E + 255) / 256;
    const int nsc = (N + 1023) / 1024;
    const int nxt = (N + 255) / 256;   // 196 row tiles

    hipMemsetAsync(cnt, 0, (size_t)N * sizeof(int), stream);

    prep_k<<<512 + nxb + nhb, 256, 0, stream>>>(W, skw, Bt, x, xb, nxv, nxb,
                                                etrg, cnt, E);

    gemm_mfma<<<nxt * 4, 256, 0, stream>>>(xb, Bt, projb, out, a_src, a_trg,
                                           s_src, s_trg, N);

    scanA<<<nsc, 1024, 0, stream>>>(cnt, off, bsum, N);
    scanBC<<<(N + 255) / 256, 256, 0, stream>>>(off, bsum, cur, N, E);

    scatter_k<<<(E + 255) / 256, 256, 0, stream>>>(esrc, etrg, cur, srcs, E);

    aggregate_wave<<<(N + 3) / 4, 256, 0, stream>>>(off, srcs, s_src, s_trg,
                                                    projb, bias, out, N);
}

// Round 8
// 282.162 us; speedup vs baseline: 1.1107x; 1.1107x over previous
//
#include <hip/hip_runtime.h>
#include <math.h>

// Problem constants (from reference): N=50000, E=800000, IN=256, H=4, F=64.
constexpr float SLOPE = 0.2f;

typedef __bf16 bf16x8 __attribute__((ext_vector_type(8)));
typedef __bf16 bf16x4 __attribute__((ext_vector_type(4)));
typedef float  f32x4  __attribute__((ext_vector_type(4)));

__device__ __forceinline__ int imin(int a, int b) { return a < b ? a : b; }

// Async global->LDS 16B copy. LDS dest must be lane-linear (wave-uniform base
// + lane*16) — our staging index order matches lane order exactly.
__device__ __forceinline__ void glds16(const void* g, void* l) {
    __builtin_amdgcn_global_load_lds(
        (const __attribute__((address_space(1))) unsigned int*)g,
        (__attribute__((address_space(3))) unsigned int*)l,
        16, 0, 0);
}

// ---------------------------------------------------------------------------
// Fused prep: [0,512) Bt transpose+cast | b==512: Wa = W @ a_{src,trg} folded
// score columns (Bt rows 512..527, rows 520+ zero) | [513,513+nxb) x->bf16
// cast | rest: target-degree histogram + per-edge rank capture (the atomic's
// return value IS the edge's slot within its target bucket — persisting it
// makes the later scatter deterministic and atomic-free).
// ---------------------------------------------------------------------------
__global__ __launch_bounds__(256) void prep_k(
    const float* __restrict__ W, const float* __restrict__ skw,
    const float* __restrict__ a_src, const float* __restrict__ a_trg,
    __bf16* __restrict__ Bt,
    const float* __restrict__ x, __bf16* __restrict__ xb, int nxv, int nxb,
    const int* __restrict__ etrg, int* __restrict__ cnt,
    int* __restrict__ rank, int E)
{
    const int b = blockIdx.x;
    if (b < 512) {
        const int i = b * 256 + threadIdx.x;     // i = n*256 + k
        const int n = i >> 8, k = i & 255;
        const float v = (n < 256) ? W[k * 256 + n] : skw[k * 256 + (n - 256)];
        Bt[i] = (__bf16)v;
    } else if (b == 512) {
        // Wa[k][c]: c<4 -> sum_f W[k, c*64+f]*a_src[c,f]; c in 4..7 -> a_trg.
        // Stored bf16 at Bt rows 512+c; rows 520..527 zeroed.
        __shared__ float lw[32][260];   // 32 W rows, padded stride
        __shared__ float la[8][64];
        const int t = threadIdx.x;
        for (int i = t; i < 512; i += 256) {
            const int row = i >> 6, f = i & 63;
            la[row][f] = (row < 4) ? a_src[row * 64 + f]
                                   : a_trg[(row - 4) * 64 + f];
        }
        const int c  = t & 15;
        const int ks = t >> 4;          // 0..15
        for (int k0 = 0; k0 < 256; k0 += 32) {
            __syncthreads();
#pragma unroll
            for (int p = 0; p < 8; ++p) {       // coalesced W rows
                const int idx = p * 256 + t;
                const int r   = idx >> 6;       // 0..31
                const int cc  = (idx & 63) * 4;
                *(float4*)&lw[r][cc] =
                    *(const float4*)(W + (size_t)(k0 + r) * 256 + cc);
            }
            __syncthreads();
            if (c < 8) {
                const int cb = (c & 3) * 64;
#pragma unroll
                for (int kk = 0; kk < 2; ++kk) {
                    const int kr = ks + kk * 16;
                    float s = 0.f;
#pragma unroll
                    for (int f = 0; f < 64; ++f)
                        s += lw[kr][cb + f] * la[c][f];
                    Bt[(size_t)(512 + c) * 256 + (k0 + kr)] = (__bf16)s;
                }
            } else {
                Bt[(size_t)(512 + c) * 256 + (k0 + ks)]      = (__bf16)0.f;
                Bt[(size_t)(512 + c) * 256 + (k0 + ks + 16)] = (__bf16)0.f;
            }
        }
    } else if (b < 513 + nxb) {
        const int gid = (b - 513) * 256 + threadIdx.x;   // 8 f32 per thread
        if (gid < nxv) {
            const float4 f0 = *(const float4*)(x + (size_t)gid * 8);
            const float4 f1 = *(const float4*)(x + (size_t)gid * 8 + 4);
            bf16x8 v;
            v[0] = (__bf16)f0.x; v[1] = (__bf16)f0.y;
            v[2] = (__bf16)f0.z; v[3] = (__bf16)f0.w;
            v[4] = (__bf16)f1.x; v[5] = (__bf16)f1.y;
            v[6] = (__bf16)f1.z; v[7] = (__bf16)f1.w;
            *(bf16x8*)(xb + (size_t)gid * 8) = v;
        }
    } else {
        const int e = (b - 513 - nxb) * 256 + threadIdx.x;
        if (e < E) rank[e] = atomicAdd(&cnt[etrg[e]], 1);
    }
}

// ---------------------------------------------------------------------------
// MFMA GEMM, 256x128 tile: C[M,512+] = xb[M,256] @ [W | skip_w | Wa].
// 1D grid, y = bid%5 INNERMOST so the 5 blocks sharing an A-tile dispatch
// back-to-back (L2/L3-temporal reuse of the 131KB xb tile).
// y=0,1 -> projb bf16 cols 0..255; y=2,3 -> out f32 (skip) cols 256..511;
// y=4  -> narrow 16-col score slice (Bt rows 512..527) writing s_src/s_trg.
// (R6/R7's in-accumulator score fold regressed the GEMM 71->90us: 256
// ds_bpermute/thread, 1.2M LDS bank conflicts, occupancy 17%. The y=4
// MFMA slice is the measured-fast score path — R3: total 308.3, gemm <71.)
// BK=32, 4 waves; A/B frag: [m|n]=lane&15, k=quad*8+j; C/D: col=lane&15,
// row=quad*4+reg.
// ---------------------------------------------------------------------------
__global__ __launch_bounds__(256, 2) void gemm_mfma(
    const __bf16* __restrict__ xb, const __bf16* __restrict__ Bt,
    __bf16* __restrict__ projb, float* __restrict__ out,
    float* __restrict__ s_src, float* __restrict__ s_trg, int M)
{
    __shared__ __bf16 As[256 * 32];   // 16 KB
    __shared__ __bf16 Bs[128 * 32];   //  8 KB

    const int t    = threadIdx.x;
    const int w    = t >> 6;
    const int lane = t & 63;
    const int q    = lane >> 4;
    const int ln   = lane & 15;

    const int bid  = blockIdx.x;
    const int bx   = bid / 5;
    const int y    = bid % 5;
    const int row0 = bx * 256;
    const int bt0  = y * 128;              // Bt row base for y<4

    f32x4 acc[4][8] = {};

    for (int k0 = 0; k0 < 256; k0 += 32) {
#pragma unroll
        for (int p = 0; p < 4; ++p) {          // A: 256 rows x 32 k
            const int idx = p * 256 + t;
            const int r   = idx >> 2;          // 0..255
            const int ko  = (idx & 3) * 8;     // 0,8,16,24
            const int ga  = imin(row0 + r, M - 1);
            glds16(xb + (size_t)ga * 256 + k0 + ko, &As[idx * 8]);
        }
        if (y < 4) {
#pragma unroll
            for (int p = 0; p < 2; ++p) {      // B: 128 rows x 32 k
                const int idx = p * 256 + t;
                const int r   = idx >> 2;      // 0..127
                const int ko  = (idx & 3) * 8;
                glds16(Bt + (size_t)(bt0 + r) * 256 + k0 + ko, &Bs[idx * 8]);
            }
        } else {
            // 16-row score slice; all 4 waves duplicate the same lane-linear
            // 1KB stage (identical src+dest per lane across waves — benign).
            const int i6 = t & 63;
            const int r  = i6 >> 2;            // 0..15
            const int ko = (i6 & 3) * 8;
            glds16(Bt + (size_t)(512 + r) * 256 + k0 + ko, &Bs[i6 * 8]);
        }
        asm volatile("s_waitcnt vmcnt(0)" ::: "memory");
        __syncthreads();

        if (y < 4) {
            bf16x8 af[4], bfr[8];
#pragma unroll
            for (int rb = 0; rb < 4; ++rb)
                af[rb] = *(const bf16x8*)&As[(w * 64 + rb * 16 + ln) * 32 + q * 8];
#pragma unroll
            for (int cb = 0; cb < 8; ++cb)
                bfr[cb] = *(const bf16x8*)&Bs[(cb * 16 + ln) * 32 + q * 8];
#pragma unroll
            for (int rb = 0; rb < 4; ++rb)
#pragma unroll
                for (int cb = 0; cb < 8; ++cb)
                    acc[rb][cb] = __builtin_amdgcn_mfma_f32_16x16x32_bf16(
                        af[rb], bfr[cb], acc[rb][cb], 0, 0, 0);
        } else {
            const bf16x8 bf0 = *(const bf16x8*)&Bs[ln * 32 + q * 8];
#pragma unroll
            for (int rb = 0; rb < 4; ++rb) {
                const bf16x8 af =
                    *(const bf16x8*)&As[(w * 64 + rb * 16 + ln) * 32 + q * 8];
                acc[rb][0] = __builtin_amdgcn_mfma_f32_16x16x32_bf16(
                    af, bf0, acc[rb][0], 0, 0, 0);
            }
        }
        __syncthreads();
    }

    if (y < 4) {
        const bool isProj  = (y < 2);
        const int  colbase = (y & 1) * 128;
#pragma unroll
        for (int rb = 0; rb < 4; ++rb) {
#pragma unroll
            for (int r = 0; r < 4; ++r) {
                const int grow = row0 + w * 64 + rb * 16 + q * 4 + r;
                if (grow < M) {
#pragma unroll
                    for (int cb = 0; cb < 8; ++cb) {
                        const float v = acc[rb][cb][r];
                        const int gcol = colbase + cb * 16 + ln;
                        if (isProj) projb[(size_t)grow * 256 + gcol] = (__bf16)v;
                        else        out[(size_t)grow * 256 + gcol]   = v;
                    }
                }
            }
        }
    } else {
#pragma unroll
        for (int rb = 0; rb < 4; ++rb) {
#pragma unroll
            for (int r = 0; r < 4; ++r) {
                const int grow = row0 + w * 64 + rb * 16 + q * 4 + r;
                if (grow < M && ln < 8) {
                    const float v = acc[rb][0][r];
                    if (ln < 4) s_src[grow * 4 + ln]       = v;
                    else        s_trg[grow * 4 + (ln - 4)] = v;
                }
            }
        }
    }
}

// ---------------------------------------------------------------------------
// Scan phase A: block-local exclusive scan of 1024-elem chunks.
// ---------------------------------------------------------------------------
__global__ __launch_bounds__(1024) void scanA(
    const int* __restrict__ cnt, int* __restrict__ off, int* __restrict__ bsum, int N)
{
    __shared__ int wsum[16];
    const int t = threadIdx.x;
    const int lane = t & 63;
    const int w = t >> 6;
    const int i = blockIdx.x * 1024 + t;
    const int v = (i < N) ? cnt[i] : 0;

    int s = v;
#pragma unroll
    for (int d = 1; d < 64; d <<= 1) {
        int o = __shfl_up(s, d);
        if (lane >= d) s += o;
    }
    if (lane == 63) wsum[w] = s;
    __syncthreads();
    if (w == 0 && lane < 16) {
        int ws = wsum[lane];
        int sc = ws;
#pragma unroll
        for (int d = 1; d < 16; d <<= 1) {
            int o = __shfl_up(sc, d);
            if (lane >= d) sc += o;
        }
        wsum[lane] = sc - ws;
    }
    __syncthreads();
    const int excl = wsum[w] + s - v;
    if (i < N) off[i] = excl;
    if (t == 1023) bsum[blockIdx.x] = excl + v;
}

// ---------------------------------------------------------------------------
// Scan phase BC fused: each block sums its <=49 preceding chunk totals.
// (cur[] no longer needed — scatter is rank-based, atomic-free.)
// ---------------------------------------------------------------------------
__global__ __launch_bounds__(256) void scanBC(
    int* __restrict__ off, const int* __restrict__ bsum, int N, int E)
{
    const int i = blockIdx.x * 256 + threadIdx.x;
    const int chunk = blockIdx.x >> 2;
    const int lane = threadIdx.x & 63;

    int v = (lane < chunk) ? bsum[lane] : 0;
#pragma unroll
    for (int d = 1; d < 64; d <<= 1) v += __shfl_xor(v, d);

    if (i < N) off[i] = off[i] + v;
    if (i == 0) off[N] = E;
}

// ---------------------------------------------------------------------------
// Scatter, atomic-free: prep already captured rank[e] (edge's slot within
// its target bucket), so placement is deterministic: 3 coalesced reads +
// one L2-resident off gather + one random 4B write. Replaces 800k atomics.
// ---------------------------------------------------------------------------
__global__ __launch_bounds__(256) void scatter_k(
    const int* __restrict__ esrc, const int* __restrict__ etrg,
    const int* __restrict__ rank, const int* __restrict__ off,
    int* __restrict__ srcs, int E)
{
    const int e = blockIdx.x * 256 + threadIdx.x;
    if (e < E) srcs[off[etrg[e]] + rank[e]] = esrc[e];
}

// ---------------------------------------------------------------------------
// Fused softmax + aggregation + skip + bias + activation.
// ONE WAVE per target node (4 nodes/block). Lane l owns feature elems
// 4l..4l+3 (bf16x4 = 8 B gather/lane), head h = l>>4.
//
// Per 8-edge batch: batch base i is wave-uniform (off[] readfirstlane'd), so
// the 8 src ids are lifted to SGPRs via v_readlane (no ds_bpermute chain) and
// gathers issue as saddr-form loads. Lane (h*16+j') computes exp(edge j',
// head h) once; e[j] distributed via one bpermute per edge.
//
// 2-deep software pipeline (A/B ping-pong, statically indexed): batch k+1's
// srcs load + s_src gather + exp + 8 projb gathers are issued BEFORE batch
// k's e-shuffles + FMAs, so gather latency hides under consume. Global-max
// shift of the reference cancels in ex/denom. out already holds the skip
// projection (gemm y=2,3).
// ---------------------------------------------------------------------------
__global__ __launch_bounds__(256) void aggregate_wave(
    const int* __restrict__ off, const int* __restrict__ srcs,
    const float* __restrict__ s_src, const float* __restrict__ s_trg,
    const __bf16* __restrict__ projb, const float* __restrict__ bias,
    float* __restrict__ out, int N)
{
    const int w = threadIdx.x >> 6;
    const int l = threadIdx.x & 63;
    const int n = blockIdx.x * 4 + w;
    if (n >= N) return;

    const int h  = l >> 4;
    const int je = l & 7;
    const float st = s_trg[n * 4 + h];
    const int b0 = __builtin_amdgcn_readfirstlane(off[n]);
    const int b1 = __builtin_amdgcn_readfirstlane(off[n + 1]);

    f32x4 acc = {0.f, 0.f, 0.f, 0.f};
    float denom = 0.f;

    int i = b0;
    const int nb = (b1 - b0) >> 3;

    int    sgA[8], sgB[8];
    bf16x4 pA[8], pB[8];
    float  exA, exB;

    // Issue batch at position i: uniform src ids -> SGPR, gathers in flight,
    // this lane's exp for (edge je, head h). Advances i.
#define ISSUE(SG, P, EX)                                                      \
    {                                                                         \
        const int sm = srcs[i + je];                                          \
        _Pragma("unroll")                                                     \
        for (int j = 0; j < 8; ++j) SG[j] = __builtin_amdgcn_readlane(sm, j); \
        _Pragma("unroll")                                                     \
        for (int j = 0; j < 8; ++j)                                           \
            P[j] = *(const bf16x4*)(projb +                                   \
                     (size_t)((unsigned)SG[j] * 256u) + l * 4);               \
        float v = s_src[sm * 4 + h] + st;                                     \
        v = v > 0.f ? v : SLOPE * v;                                          \
        EX = __expf(v);                                                       \
        i += 8;                                                               \
    }

    // Consume a batch: distribute exp weights (1 bpermute/edge) and FMA.
#define CONSUME(P, EX)                                                        \
    {                                                                         \
        _Pragma("unroll")                                                     \
        for (int j = 0; j < 8; ++j) {                                         \
            const float e = __shfl(EX, (l & 48) | j);                         \
            denom += e;                                                       \
            acc[0] += e * (float)P[j][0];                                     \
            acc[1] += e * (float)P[j][1];                                     \
            acc[2] += e * (float)P[j][2];                                     \
            acc[3] += e * (float)P[j][3];                                     \
        }                                                                     \
    }

    if (nb > 0) {
        ISSUE(sgA, pA, exA);
        int rem = nb - 1;
        while (rem >= 2) {
            ISSUE(sgB, pB, exB);
            CONSUME(pA, exA);
            ISSUE(sgA, pA, exA);
            CONSUME(pB, exB);
            rem -= 2;
        }
        if (rem == 1) {
            ISSUE(sgB, pB, exB);
            CONSUME(pA, exA);
            CONSUME(pB, exB);
        } else {
            CONSUME(pA, exA);
        }
    }
#undef ISSUE
#undef CONSUME

    for (; i < b1; ++i) {
        const int s = srcs[i];
        float v = s_src[s * 4 + h] + st;
        v = v > 0.f ? v : SLOPE * v;
        const float ex = __expf(v);
        denom += ex;
        const bf16x4 p = *(const bf16x4*)(projb + (size_t)((unsigned)s * 256u) + l * 4);
        acc[0] += ex * (float)p[0];
        acc[1] += ex * (float)p[1];
        acc[2] += ex * (float)p[2];
        acc[3] += ex * (float)p[3];
    }

    const size_t o = (size_t)n * 256 + l * 4;
    const float4 sk = *(const float4*)(out + o);
    const float4 b4 = *(const float4*)(bias + l * 4);
    const float inv = 1.f / (denom + 1e-16f);
    float4 r;
    r.x = acc[0] * inv + sk.x + b4.x;
    r.y = acc[1] * inv + sk.y + b4.y;
    r.z = acc[2] * inv + sk.z + b4.z;
    r.w = acc[3] * inv + sk.w + b4.w;
    r.x = r.x > 0.f ? r.x : SLOPE * r.x;
    r.y = r.y > 0.f ? r.y : SLOPE * r.y;
    r.z = r.z > 0.f ? r.z : SLOPE * r.z;
    r.w = r.w > 0.f ? r.w : SLOPE * r.w;
    *(float4*)(out + o) = r;
}

extern "C" void kernel_launch(void* const* d_in, const int* in_sizes, int n_in,
                              void* d_out, int out_size, void* d_ws, size_t ws_size,
                              hipStream_t stream)
{
    const float* x     = (const float*)d_in[0];
    const float* W     = (const float*)d_in[1];
    const float* a_src = (const float*)d_in[2];
    const float* a_trg = (const float*)d_in[3];
    const float* skw   = (const float*)d_in[4];
    const float* bias  = (const float*)d_in[5];
    const int*   esrc  = (const int*)d_in[6];
    const int*   etrg  = (const int*)d_in[7];

    const int N = in_sizes[0] / 256;   // 50000
    const int E = in_sizes[6];         // 800000
    float* out = (float*)d_out;

    // workspace: projb bf16[N*256] | Bt bf16[528*256] | xb bf16[N*256] |
    //            s_src f32[4N] | s_trg f32[4N] | cnt[N] | off[N+1] |
    //            bsum[64] | srcs[E] | rank[E]
    __bf16* projb = (__bf16*)d_ws;
    __bf16* Bt    = projb + (size_t)N * 256;
    __bf16* xb    = Bt + 528 * 256;
    float*  s_src = (float*)(xb + (size_t)N * 256);
    float*  s_trg = s_src + (size_t)N * 4;
    int*    cnt   = (int*)(s_trg + (size_t)N * 4);
    int*    off   = cnt + N;
    int*    bsum  = off + (N + 1);
    int*    srcs  = bsum + 64;
    int*    rank  = srcs + E;

    const int nxv = (N * 256) / 8;
    const int nxb = (nxv + 255) / 256;
    const int nhb = (E + 255) / 256;
    const int nsc = (N + 1023) / 1024;
    const int nxt = (N + 255) / 256;   // 196 row tiles

    hipMemsetAsync(cnt, 0, (size_t)N * sizeof(int), stream);

    prep_k<<<513 + nxb + nhb, 256, 0, stream>>>(W, skw, a_src, a_trg, Bt,
                                                x, xb, nxv, nxb, etrg, cnt,
                                                rank, E);

    gemm_mfma<<<nxt * 5, 256, 0, stream>>>(xb, Bt, projb, out, s_src, s_trg, N);

    scanA<<<nsc, 1024, 0, stream>>>(cnt, off, bsum, N);
    scanBC<<<(N + 255) / 256, 256, 0, stream>>>(off, bsum, N, E);

    scatter_k<<<(E + 255) / 256, 256, 0, stream>>>(esrc, etrg, rank, off,
                                                   srcs, E);

    aggregate_wave<<<(N + 3) / 4, 256, 0, stream>>>(off, srcs, s_src, s_trg,
                                                    projb, bias, out, N);
}